// Round 21
// baseline (530.471 us; speedup 1.0000x reference)
//
#include <hip/hip_runtime.h>

// MLPP: 8x 256x256 GEMMs over gathered views of x[4,32,32,32,256] (fp32 in/out).
// pack -> k_att (c-QUARTER blocks, 32K LDS -> 4 blocks/CU) -> k_hw (c-half, 2/CU)
//      -> k_comb -> k_tp -> d_out
// r21 = r20 with the k_att grid fixed: 2048 blocks (512 tiles x 4 quarters), was 4096 -> OOB.

typedef __attribute__((ext_vector_type(8))) short bf16x8;
typedef __attribute__((ext_vector_type(8))) unsigned short u16x8;
typedef __attribute__((ext_vector_type(4))) float f32x4;
typedef __attribute__((ext_vector_type(4))) unsigned short u16x4;
typedef unsigned short u16;
typedef unsigned int u32;

#define DEV __device__ __forceinline__

DEV u16 f2b(float f) {  // fp32 -> bf16 RNE
  union { float f; u32 u; } v; v.f = f;
  u32 r = v.u + 0x7FFFu + ((v.u >> 16) & 1u);
  return (u16)(r >> 16);
}
DEV float b2f(u16 b) {
  union { u32 u; float f; } v; v.u = ((u32)b) << 16; return v.f;
}

// 512B-pitch LDS tiles, XOR swizzle over 16B slots (32 slots/row).
DEV int lds_off(int row, int colByte) {
  return (row << 9) + (colByte ^ ((row & 31) << 4));
}
// 256B-pitch tiles (16 slots/row), simple key.
DEV int lds_off256(int row, int colByte) {
  return (row << 8) + (colByte ^ ((row & 15) << 4));
}
// 128B-pitch tiles (8 slots/row).
DEV int lds_off128(int row, int colByte) {
  return (row << 7) + (colByte ^ ((row & 7) << 4));
}
// 256B-pitch tiles, composite key: lane-varying for row strides 1 AND 16.
DEV int lds_offH(int row, int colByte) {
  return (row << 8) + (colByte ^ (((row ^ (row >> 4)) & 15) << 4));
}
DEV bf16x8 ld_lds(const u16* lds, int row, int colByte) {
  return *(const bf16x8*)((const char*)lds + lds_off(row, colByte));
}
DEV bf16x8 ld_glb(const u16* g, int row, int kByte) {  // row-major [.][256] bf16, cached
  return *(const bf16x8*)((const char*)g + (row << 9) + kByte);
}
DEV void stf4_nt(float* p, f32x4 v) { __builtin_nontemporal_store(v, (f32x4*)p); }

template <int MI, int NJ>
DEV void zero_acc(f32x4 acc[MI][NJ]) {
#pragma unroll
  for (int i = 0; i < MI; ++i)
#pragma unroll
    for (int j = 0; j < NJ; ++j) {
      acc[i][j][0] = 0.f; acc[i][j][1] = 0.f; acc[i][j][2] = 0.f; acc[i][j][3] = 0.f;
    }
}

// D[m][n] = sum_k P[m][k] * Q[n][k], K=256. MI/NJ = 16x16 tiles per wave.
template <int MI, int NJ, typename LA, typename LB>
DEV void gemmT(LA loadA, LB loadB, f32x4 acc[MI][NJ]) {
#pragma unroll
  for (int kk = 0; kk < 8; ++kk) {
    bf16x8 a[MI], b[NJ];
#pragma unroll
    for (int i = 0; i < MI; ++i) a[i] = loadA(i, kk);
#pragma unroll
    for (int j = 0; j < NJ; ++j) b[j] = loadB(j, kk);
#pragma unroll
    for (int i = 0; i < MI; ++i)
#pragma unroll
      for (int j = 0; j < NJ; ++j)
        acc[i][j] = __builtin_amdgcn_mfma_f32_16x16x32_bf16(a[i], b[j], acc[i][j], 0, 0, 0);
  }
}

#define WAVE_SETUP                  \
  const int tid = threadIdx.x;      \
  const int lane = tid & 63;        \
  const int wave = tid >> 6;        \
  const int wm = wave >> 2;         \
  const int wn = wave & 3;          \
  const int lr = lane & 15;         \
  const int lk = lane >> 4;

// ---------- weight pack: WT[s][n*256+k] = W_s[k*256+n] (+I for s==7) ----------
__global__ void k_pack_all(const float* W0, const float* W1p, const float* W2p,
                           const float* W3p, const float* W4p, const float* W5p,
                           const float* W6p, const float* W7p, u16* __restrict__ WT) {
  int bi = blockIdx.x;
  int wsel = bi >> 8, n = bi & 255;
  const float* W;
  switch (wsel) {
    case 0: W = W0; break; case 1: W = W1p; break; case 2: W = W2p; break;
    case 3: W = W3p; break; case 4: W = W4p; break; case 5: W = W5p; break;
    case 6: W = W6p; break; default: W = W7p; break;
  }
  u16* dst = WT + wsel * 65536;
  int k0 = threadIdx.x * 4;
#pragma unroll
  for (int i = 0; i < 4; ++i) {
    int k = k0 + i;
    float v = __builtin_nontemporal_load(W + k * 256 + n);
    if (wsel == 7 && k == n) v += 1.0f;
    dst[n * 256 + k] = f2b(v);
  }
}

// ---------- att: D[p][c] = sum_q Wa[q][p] X[q][c] (+b_attn[p]); c-QUARTER blocks ----------
// XT = [c-quarter 64][q 256] (32 KiB) -> 4 blocks/CU. Also emits xbf for this quarter.
__global__ __launch_bounds__(512, 4) void k_att(const float* __restrict__ x,
    const u16* __restrict__ WTattn, const float* __restrict__ b_attn,
    u16* __restrict__ att, u16* __restrict__ xbf) {
  __shared__ alignas(16) u16 XT[16384];  // 32 KiB: [cloc 64][q 256] (512B pitch rows)
  WAVE_SETUP;
  const int cq = blockIdx.x & 3;
  const int t = blockIdx.x >> 2;
  const int d = t & 31, w1 = (t >> 5) & 1, h1 = (t >> 6) & 1, b = t >> 7;
  const int B0 = (((b * 32 + h1 * 16) * 32 + w1 * 16) * 32 + d) * 256;

  // A: transposed stage, conflict-free: thread = one c-row, 8 consecutive q,
  // single aligned u16x8 LDS write. 2048 u16x8 total (4 iters/thread).
  for (int i = tid; i < 2048; i += 512) {
    int cloc = i & 63;
    int q8 = i >> 6;
    u16x8 pk;
#pragma unroll
    for (int jj = 0; jj < 8; ++jj) {
      int q = q8 * 8 + jj;
      pk[jj] = f2b(x[B0 + (q >> 4) * 262144 + (q & 15) * 8192 + cq * 64 + cloc]);
    }
    *(u16x8*)((char*)XT + lds_off(cloc, q8 * 16)) = pk;
  }
  // B: xbf emission — coalesced float4 re-read (L2-hot from loop A), quarter cols
  for (int i = tid; i < 4096; i += 512) {
    int q = i >> 4;
    int c4 = (i & 15) << 2;
    const int gofs = B0 + (q >> 4) * 262144 + (q & 15) * 8192 + cq * 64 + c4;
    const f32x4 v = *(const f32x4*)(x + gofs);
    u16x4 pk;
    pk[0] = f2b(v[0]); pk[1] = f2b(v[1]); pk[2] = f2b(v[2]); pk[3] = f2b(v[3]);
    *(u16x4*)(xbf + gofs) = pk;
  }
  __syncthreads();

  // GEMM: M=256 p (wm:8 tiles), N=64 cloc (wn:1 tile each)
  f32x4 acc[8][1];
  zero_acc<8, 1>(acc);
  gemmT<8, 1>(
      [&](int i, int kk) { return ld_glb(WTattn, wm * 128 + i * 16 + lr, kk * 64 + lk * 16); },
      [&](int j, int kk) { return ld_lds(XT, wn * 16 + lr, kk * 64 + lk * 16); },
      acc);

  __syncthreads();  // XT dead; reuse as [p 256][c-quarter 64] bounce (128B pitch)
#pragma unroll
  for (int i = 0; i < 8; ++i)
#pragma unroll
    for (int r = 0; r < 4; ++r) {
      int p = wm * 128 + i * 16 + lk * 4 + r;
      int cl = wn * 16 + lr;
      XT[lds_off128(p, cl * 2) >> 1] = f2b(acc[i][0][r] + b_attn[p]);
    }
  __syncthreads();
  u16* out = att + t * 65536 + cq * 64;
  for (int i = tid; i < 2048; i += 512) {  // 256 rows x 8 slots
    int p = i >> 3, sB = (i & 7) << 4;
    bf16x8 v = *(const bf16x8*)((const char*)XT + p * 128 + sB);
    int c8l = (sB ^ ((p & 7) << 4)) >> 1;
    *(bf16x8*)(out + p * 256 + c8l) = v;
  }
}

// ---------- k_hw: h and w GEMMs from xbf; c-HALF blocks (80K LDS, 2/CU) ----------
__global__ __launch_bounds__(512, 2) void k_hw(const u16* __restrict__ xbf,
    const u16* __restrict__ WTh, const u16* __restrict__ WTw,
    u16* __restrict__ h_out, u16* __restrict__ w_out) {
  __shared__ alignas(16) u16 XS[32768];  // 64 KiB [pos 256][c-half 128], lds_offH
  __shared__ alignas(16) u16 BB[8192];   // 16 KiB bounce [64][128], lds_off256
  WAVE_SETUP;
  const int ch = blockIdx.x & 1;
  const int t = blockIdx.x >> 1;
  const int d = t & 31, w1 = (t >> 5) & 1, h1 = (t >> 6) & 1, b = t >> 7;
  const int B0 = (((b * 32 + h1 * 16) * 32 + w1 * 16) * 32 + d) * 256;
  u16* h_t = h_out + t * 65536 + ch * 128;
  u16* w_t = w_out + t * 65536 + ch * 128;

  for (int i = tid; i < 4096; i += 512) {
    int pos = i >> 4, c8 = (i & 15) << 3;
    u16x8 v = *(const u16x8*)(xbf + B0 + (pos >> 4) * 262144 + (pos & 15) * 8192 +
                              ch * 128 + c8);
    *(u16x8*)((char*)XS + lds_offH(pos, c8 * 2)) = v;
  }
  __syncthreads();

  // ---- h phases: 4 n-chunks ----
  for (int s = 0; s < 4; ++s) {
    f32x4 hacc[4][1];
    zero_acc<4, 1>(hacc);
    gemmT<4, 1>(
        [&](int i, int kk) {
          int k = kk * 32 + lk * 8;
          return *(const bf16x8*)((const char*)XS +
                                  lds_offH((k >> 4) * 16 + lr, (wm * 4 + i) * 32 + (k & 15) * 2));
        },
        [&](int j, int kk) { return ld_glb(WTh, s * 64 + wn * 16 + lr, kk * 64 + lk * 16); },
        hacc);
    __syncthreads();
#pragma unroll
    for (int i = 0; i < 4; ++i)
#pragma unroll
      for (int r = 0; r < 4; ++r)
        BB[lds_off256(wn * 16 + lk * 4 + r, ((wm * 4 + i) * 16 + lr) * 2) >> 1] =
            f2b(hacc[i][0][r]);
    __syncthreads();
    for (int i2 = tid; i2 < 1024; i2 += 512) {
      int posl = i2 >> 4, sB = (i2 & 15) << 4;
      bf16x8 v = *(const bf16x8*)((const char*)BB + posl * 256 + sB);
      int c8l = (sB ^ ((posl & 15) << 4)) >> 1;
      *(bf16x8*)(h_t + (s * 64 + posl) * 256 + c8l) = v;
    }
  }

  // ---- w phases: 4 n-chunks ----
  for (int q = 0; q < 4; ++q) {
    f32x4 wacc[4][1];
    zero_acc<4, 1>(wacc);
    gemmT<4, 1>(
        [&](int i, int kk) {
          int k = kk * 32 + lk * 8;
          return *(const bf16x8*)((const char*)XS +
                                  lds_offH(lr * 16 + (k >> 4), (wm * 4 + i) * 32 + (k & 15) * 2));
        },
        [&](int j, int kk) { return ld_glb(WTw, q * 64 + wn * 16 + lr, kk * 64 + lk * 16); },
        wacc);
    __syncthreads();
#pragma unroll
    for (int i = 0; i < 4; ++i)
#pragma unroll
      for (int r = 0; r < 4; ++r)
        BB[lds_off256((lk * 4 + r) * 4 + wn, ((wm * 4 + i) * 16 + lr) * 2) >> 1] =
            f2b(wacc[i][0][r]);
    __syncthreads();
    for (int i2 = tid; i2 < 1024; i2 += 512) {
      int rb = i2 >> 4, sB = (i2 & 15) << 4;
      bf16x8 v = *(const bf16x8*)((const char*)BB + rb * 256 + sB);
      int c8l = (sB ^ ((rb & 15) << 4)) >> 1;
      int pos = (rb >> 2) * 16 + 4 * q + (rb & 3);
      *(bf16x8*)(w_t + pos * 256 + c8l) = v;
    }
  }
}

// ---------- k_comb: single 64K tile; c-GEMM + streams + W1 + residual(xbf) -> x1 ----------
__global__ __launch_bounds__(512, 2) void k_comb(const u16* __restrict__ xbf,
    const u16* __restrict__ h_out, const u16* __restrict__ w_out, const u16* __restrict__ att,
    const float* __restrict__ bh, const float* __restrict__ bw, const float* __restrict__ bc,
    const u16* __restrict__ WTc, const u16* __restrict__ WT1, const float* __restrict__ b1,
    u16* __restrict__ x1) {
  __shared__ alignas(16) u16 T[32768];  // 64 KiB multi-use tile [posl 128][c 256]
  WAVE_SETUP;
  const int ph = blockIdx.x & 1;
  const int t = blockIdx.x >> 1;
  const int d = t & 31, w1 = (t >> 5) & 1, h1 = (t >> 6) & 1, b = t >> 7;
  const int B0 = (((b * 32 + h1 * 16) * 32 + w1 * 16) * 32 + d) * 256;
  const u16* h_t = h_out + t * 65536;
  const u16* w_t = w_out + t * 65536;
  const u16* att_t = att + t * 65536;

  // 1. stage from xbf (wide, coalesced)
  for (int i = tid; i < 4096; i += 512) {
    int posl = i >> 5, c8 = (i & 31) << 3;
    int pos = ph * 128 + posl;
    u16x8 v = *(const u16x8*)(xbf + B0 + (pos >> 4) * 262144 + (pos & 15) * 8192 + c8);
    *(u16x8*)((char*)T + lds_off(posl, c8 * 2)) = v;
  }
  __syncthreads();

  // 2. c-GEMM (Wc read once per block)
  f32x4 acc[4][4];
  zero_acc<4, 4>(acc);
  gemmT<4, 4>(
      [&](int i, int kk) { return ld_lds(T, wm * 64 + i * 16 + lr, kk * 64 + lk * 16); },
      [&](int j, int kk) { return ld_glb(WTc, wn * 64 + j * 16 + lr, kk * 64 + lk * 16); },
      acc);
  __syncthreads();  // all T reads retired

  // 3. T <- acc + bc + bh + bw
#pragma unroll
  for (int i = 0; i < 4; ++i) {
    int lh = ph * 8 + wm * 4 + i;
#pragma unroll
    for (int j = 0; j < 4; ++j) {
      float bcv = bc[wn * 64 + j * 16 + lr];
#pragma unroll
      for (int r = 0; r < 4; ++r) {
        int posl = wm * 64 + i * 16 + lk * 4 + r;
        int n = wn * 64 + j * 16 + lr;
        float v = acc[i][j][r] + bcv + bh[lh * 16 + lr] + bw[(lk * 4 + r) * 16 + lr];
        T[lds_off(posl, n * 2) >> 1] = f2b(v);
      }
    }
  }
  __syncthreads();

  // 4. streamed: T = (1+att) * (T + h + w)
  for (int i2 = tid; i2 < 4096; i2 += 512) {
    int posl = i2 >> 5, c8 = (i2 & 31) << 3;
    int pos = ph * 128 + posl;
    u16x8 hv = *(const u16x8*)(h_t + pos * 256 + c8);
    u16x8 wv = *(const u16x8*)(w_t + pos * 256 + c8);
    u16x8 av = *(const u16x8*)(att_t + pos * 256 + c8);
    u16x8* p = (u16x8*)((char*)T + lds_off(posl, c8 * 2));
    u16x8 cur = *p, o;
#pragma unroll
    for (int j = 0; j < 8; ++j)
      o[j] = f2b((1.0f + b2f(av[j])) * (b2f(cur[j]) + b2f(hv[j]) + b2f(wv[j])));
    *p = o;
  }
  __syncthreads();

  // 5. W1-GEMM (W1 read once per block)
  zero_acc<4, 4>(acc);
  gemmT<4, 4>(
      [&](int i, int kk) { return ld_lds(T, wm * 64 + i * 16 + lr, kk * 64 + lk * 16); },
      [&](int j, int kk) { return ld_glb(WT1, wn * 64 + j * 16 + lr, kk * 64 + lk * 16); },
      acc);
  __syncthreads();

  // 6. T <- acc + b1
#pragma unroll
  for (int i = 0; i < 4; ++i)
#pragma unroll
    for (int j = 0; j < 4; ++j) {
      float b1v = b1[wn * 64 + j * 16 + lr];
#pragma unroll
      for (int r = 0; r < 4; ++r) {
        int posl = wm * 64 + i * 16 + lk * 4 + r;
        int n = wn * 64 + j * 16 + lr;
        T[lds_off(posl, n * 2) >> 1] = f2b(acc[i][j][r] + b1v);
      }
    }
  __syncthreads();

  // 7. x1 = T + xbf (coalesced re-read, L3-hot); x-layout store
  for (int i2 = tid; i2 < 4096; i2 += 512) {
    int posl = i2 >> 5, sB = (i2 & 31) << 4;
    bf16x8 v = *(const bf16x8*)((const char*)T + posl * 512 + sB);
    int c8 = (sB ^ ((posl & 31) << 4)) >> 1;
    int pos = ph * 128 + posl;
    const int gofs = B0 + (pos >> 4) * 262144 + (pos & 15) * 8192 + c8;
    u16x8 xv = *(const u16x8*)(xbf + gofs);
    u16x8 o;
#pragma unroll
    for (int j = 0; j < 8; ++j) o[j] = f2b(b2f((u16)v[j]) + b2f(xv[j]));
    *(u16x8*)(x1 + gofs) = o;
  }
}

// ---------- k_tp: FUSED d+W2+W3, 128-row blocks, x1 kept in regs for residual ----------
__global__ __launch_bounds__(512, 2) void k_tp(const u16* __restrict__ x1,
    const u16* __restrict__ WTd, const u16* __restrict__ WT2, const u16* __restrict__ WT3p,
    const float* __restrict__ bd, const float* __restrict__ b2, const float* __restrict__ b3,
    float* __restrict__ outp) {
  __shared__ alignas(16) u16 T[32768];  // 64 KiB [R 128][c 256], R=(wloLoc,ld)
  WAVE_SETUP;
  const int bid = blockIdx.x;
  const int wg = bid & 3, d1 = (bid >> 2) & 1, h = (bid >> 3) & 31, b = bid >> 8;
  const int W0 = (b * 32 + h) * 32 + wg * 8;

  // 1. stage x1 rows; KEEP staged values in regs for the phase-6 residual
  u16x8 xkeep[8];
#pragma unroll
  for (int u = 0; u < 8; ++u) {
    int i = tid + u * 512;
    int Rl = i >> 5, c8 = (i & 31) << 3;
    const u16x8 v = *(const u16x8*)(x1 + (size_t)(W0 + (Rl >> 4)) * 8192 +
                                    (d1 * 16 + (Rl & 15)) * 256 + c8);
    xkeep[u] = v;
    *(u16x8*)((char*)T + lds_off(Rl, c8 * 2)) = v;
  }
  __syncthreads();

  // 2. d-GEMM: m=(wloLoc,lc) 128, n=(ld',g) 256, k=(ld,g') 256
  f32x4 acc[4][4];
  zero_acc<4, 4>(acc);
  gemmT<4, 4>(
      [&](int i, int kk) {
        int k = kk * 32 + lk * 8;
        int mt = wm * 4 + i;
        return *(const bf16x8*)((const char*)T + lds_off(mt * 16 + (k >> 4),
                                                         lr * 32 + (k & 15) * 2));
      },
      [&](int j, int kk) { return ld_glb(WTd, wn * 64 + j * 16 + lr, kk * 64 + lk * 16); },
      acc);
  __syncthreads();  // all T reads retired before overwrite

  // 3. T <- xd rows: (mloc,n) -> row=((mloc>>4)<<4)+(n>>4), col=((mloc&15)<<4)+(n&15)
#pragma unroll
  for (int i = 0; i < 4; ++i)
#pragma unroll
    for (int j = 0; j < 4; ++j)
#pragma unroll
      for (int r = 0; r < 4; ++r) {
        int mloc = wm * 64 + i * 16 + lk * 4 + r;
        int n = wn * 64 + j * 16 + lr;
        int row = ((mloc >> 4) << 4) + (n >> 4);
        int col = ((mloc & 15) << 4) + (n & 15);
        T[lds_off(row, col * 2) >> 1] = f2b(acc[i][j][r] + bd[n]);
      }
  __syncthreads();

  // 4. W2-GEMM: A = T (xd rows)
  zero_acc<4, 4>(acc);
  gemmT<4, 4>(
      [&](int i, int kk) { return ld_lds(T, (wm * 4 + i) * 16 + lr, kk * 64 + lk * 16); },
      [&](int j, int kk) { return ld_glb(WT2, wn * 64 + j * 16 + lr, kk * 64 + lk * 16); },
      acc);
  __syncthreads();  // T reads retired

  // 5. T <- acc + b2
#pragma unroll
  for (int i = 0; i < 4; ++i)
#pragma unroll
    for (int j = 0; j < 4; ++j) {
      float b2v = b2[wn * 64 + j * 16 + lr];
#pragma unroll
      for (int r = 0; r < 4; ++r) {
        int mloc = wm * 64 + i * 16 + lk * 4 + r;
        int n = wn * 64 + j * 16 + lr;
        T[lds_off(mloc, n * 2) >> 1] = f2b(acc[i][j][r] + b2v);
      }
    }
  __syncthreads();

  // 6. T += x1 (from regs — no global re-read)
#pragma unroll
  for (int u = 0; u < 8; ++u) {
    int i = tid + u * 512;
    int Rl = i >> 5, c8 = (i & 31) << 3;
    u16x8* p = (u16x8*)((char*)T + lds_off(Rl, c8 * 2));
    u16x8 cur = *p, o;
#pragma unroll
    for (int j = 0; j < 8; ++j) o[j] = f2b(b2f(cur[j]) + b2f(xkeep[u][j]));
    *p = o;
  }
  __syncthreads();

  // 7. W3-GEMM: A = T (x2 rows), B = (W3+I)^T
  zero_acc<4, 4>(acc);
  gemmT<4, 4>(
      [&](int i, int kk) { return ld_lds(T, (wm * 4 + i) * 16 + lr, kk * 64 + lk * 16); },
      [&](int j, int kk) { return ld_glb(WT3p, wn * 64 + j * 16 + lr, kk * 64 + lk * 16); },
      acc);

  // 8. fp32 out via 2-half T bounce ([64][256] f32 = 64K), float4 nt stores
  float* Tf = (float*)T;
#pragma unroll
  for (int half = 0; half < 2; ++half) {
    __syncthreads();  // T reads (W3 or prev half's stores) retired
    if (wm == half) {
#pragma unroll
      for (int i = 0; i < 4; ++i)
#pragma unroll
        for (int j = 0; j < 4; ++j)
#pragma unroll
          for (int r = 0; r < 4; ++r) {
            int row = i * 16 + lk * 4 + r;  // 0..63
            int n = wn * 64 + j * 16 + lr;
            Tf[row * 256 + n] = acc[i][j][r] + b3[n];
          }
    }
    __syncthreads();
    for (int i2 = tid; i2 < 4096; i2 += 512) {
      int row = i2 >> 6, c4 = (i2 & 63) << 2;
      int Rg = half * 64 + row;
      f32x4 v = *(const f32x4*)(Tf + row * 256 + c4);
      stf4_nt(outp + (size_t)(W0 + (Rg >> 4)) * 8192 + (d1 * 16 + (Rg & 15)) * 256 + c4, v);
    }
  }
}

extern "C" void kernel_launch(void* const* d_in, const int* in_sizes, int n_in,
                              void* d_out, int out_size, void* d_ws, size_t ws_size,
                              hipStream_t stream) {
  (void)in_sizes; (void)n_in; (void)out_size; (void)ws_size;
  const float* x      = (const float*)d_in[0];
  const float* W_h    = (const float*)d_in[1];
  const float* b_h    = (const float*)d_in[2];
  const float* W_w    = (const float*)d_in[3];
  const float* b_w    = (const float*)d_in[4];
  const float* W_c    = (const float*)d_in[5];
  const float* b_c    = (const float*)d_in[6];
  const float* W_d    = (const float*)d_in[7];
  const float* b_d    = (const float*)d_in[8];
  const float* W_attn = (const float*)d_in[9];
  const float* b_attn = (const float*)d_in[10];
  const float* W_1    = (const float*)d_in[11];
  const float* b_1    = (const float*)d_in[12];
  const float* W_2    = (const float*)d_in[13];
  const float* b_2    = (const float*)d_in[14];
  const float* W_3    = (const float*)d_in[15];
  const float* b_3    = (const float*)d_in[16];
  float* outp = (float*)d_out;

  u16* WT = (u16*)d_ws;             // 8 * 65536 bf16 (1 MiB)
  u16* R1 = WT + 8 * 65536;         // 64 MiB: xbf (x-layout) -> x1 (x-layout, block-local overlay)
  u16* R2 = R1 + 33554432;          // 64 MiB: att scratch
  u16* HOS = (u16*)d_out;           // h stream: first 64 MiB of d_out (dead after k_comb)
  u16* WOS = HOS + 33554432;        // w stream: second 64 MiB of d_out (dead after k_comb)

  // slots: 0:h 1:w 2:c 3:attn 4:W1 5:Wd 6:W2 7:W3(+I)
  k_pack_all<<<2048, 64, 0, stream>>>(W_h, W_w, W_c, W_attn, W_1, W_d, W_2, W_3, WT);

  k_att <<<2048, 512, 0, stream>>>(x, WT + 3 * 65536, b_attn, R2, R1);
  k_hw  <<<1024, 512, 0, stream>>>(R1, WT + 0 * 65536, WT + 1 * 65536, HOS, WOS);
  k_comb<<<1024, 512, 0, stream>>>(R1, HOS, WOS, R2, b_h, b_w, b_c,
                                   WT + 2 * 65536, WT + 4 * 65536, b_1, R1);
  k_tp  <<<1024, 512, 0, stream>>>(R1, WT + 5 * 65536, WT + 6 * 65536, WT + 7 * 65536,
                                   b_d, b_2, b_3, outp);
}

// Round 22
// 489.492 us; speedup vs baseline: 1.0837x; 1.0837x over previous
//
#include <hip/hip_runtime.h>

// MLPP: 8x 256x256 GEMMs over gathered views of x[4,32,32,32,256] (fp32 in/out).
// pack -> k_att (c-HALF blocks, 64K XT, 2/CU — r19-proven) -> k_hw (c-half, 2/CU)
//      -> k_comb -> k_tp -> d_out
// r22 = r19 exact configuration (best measured: 490.7 us). r21's k_att c-quarter
// regressed (stage:compute ratio doubled) -> reverted.

typedef __attribute__((ext_vector_type(8))) short bf16x8;
typedef __attribute__((ext_vector_type(8))) unsigned short u16x8;
typedef __attribute__((ext_vector_type(4))) float f32x4;
typedef __attribute__((ext_vector_type(4))) unsigned short u16x4;
typedef unsigned short u16;
typedef unsigned int u32;

#define DEV __device__ __forceinline__

DEV u16 f2b(float f) {  // fp32 -> bf16 RNE
  union { float f; u32 u; } v; v.f = f;
  u32 r = v.u + 0x7FFFu + ((v.u >> 16) & 1u);
  return (u16)(r >> 16);
}
DEV float b2f(u16 b) {
  union { u32 u; float f; } v; v.u = ((u32)b) << 16; return v.f;
}

// 512B-pitch LDS tiles, XOR swizzle over 16B slots (32 slots/row).
DEV int lds_off(int row, int colByte) {
  return (row << 9) + (colByte ^ ((row & 31) << 4));
}
// 256B-pitch tiles (16 slots/row), simple key.
DEV int lds_off256(int row, int colByte) {
  return (row << 8) + (colByte ^ ((row & 15) << 4));
}
// 256B-pitch tiles, composite key: lane-varying for row strides 1 AND 16.
DEV int lds_offH(int row, int colByte) {
  return (row << 8) + (colByte ^ (((row ^ (row >> 4)) & 15) << 4));
}
DEV bf16x8 ld_lds(const u16* lds, int row, int colByte) {
  return *(const bf16x8*)((const char*)lds + lds_off(row, colByte));
}
DEV bf16x8 ld_glb(const u16* g, int row, int kByte) {  // row-major [.][256] bf16, cached
  return *(const bf16x8*)((const char*)g + (row << 9) + kByte);
}
DEV void stf4_nt(float* p, f32x4 v) { __builtin_nontemporal_store(v, (f32x4*)p); }

template <int MI, int NJ>
DEV void zero_acc(f32x4 acc[MI][NJ]) {
#pragma unroll
  for (int i = 0; i < MI; ++i)
#pragma unroll
    for (int j = 0; j < NJ; ++j) {
      acc[i][j][0] = 0.f; acc[i][j][1] = 0.f; acc[i][j][2] = 0.f; acc[i][j][3] = 0.f;
    }
}

// D[m][n] = sum_k P[m][k] * Q[n][k], K=256. MI/NJ = 16x16 tiles per wave.
template <int MI, int NJ, typename LA, typename LB>
DEV void gemmT(LA loadA, LB loadB, f32x4 acc[MI][NJ]) {
#pragma unroll
  for (int kk = 0; kk < 8; ++kk) {
    bf16x8 a[MI], b[NJ];
#pragma unroll
    for (int i = 0; i < MI; ++i) a[i] = loadA(i, kk);
#pragma unroll
    for (int j = 0; j < NJ; ++j) b[j] = loadB(j, kk);
#pragma unroll
    for (int i = 0; i < MI; ++i)
#pragma unroll
      for (int j = 0; j < NJ; ++j)
        acc[i][j] = __builtin_amdgcn_mfma_f32_16x16x32_bf16(a[i], b[j], acc[i][j], 0, 0, 0);
  }
}

#define WAVE_SETUP                  \
  const int tid = threadIdx.x;      \
  const int lane = tid & 63;        \
  const int wave = tid >> 6;        \
  const int wm = wave >> 2;         \
  const int wn = wave & 3;          \
  const int lr = lane & 15;         \
  const int lk = lane >> 4;

// ---------- weight pack: WT[s][n*256+k] = W_s[k*256+n] (+I for s==7) ----------
__global__ void k_pack_all(const float* W0, const float* W1p, const float* W2p,
                           const float* W3p, const float* W4p, const float* W5p,
                           const float* W6p, const float* W7p, u16* __restrict__ WT) {
  int bi = blockIdx.x;
  int wsel = bi >> 8, n = bi & 255;
  const float* W;
  switch (wsel) {
    case 0: W = W0; break; case 1: W = W1p; break; case 2: W = W2p; break;
    case 3: W = W3p; break; case 4: W = W4p; break; case 5: W = W5p; break;
    case 6: W = W6p; break; default: W = W7p; break;
  }
  u16* dst = WT + wsel * 65536;
  int k0 = threadIdx.x * 4;
#pragma unroll
  for (int i = 0; i < 4; ++i) {
    int k = k0 + i;
    float v = __builtin_nontemporal_load(W + k * 256 + n);
    if (wsel == 7 && k == n) v += 1.0f;
    dst[n * 256 + k] = f2b(v);
  }
}

// ---------- att: D[p][c] = sum_q Wa[q][p] X[q][c] (+b_attn[p]); c-half blocks ----------
__global__ __launch_bounds__(512, 4) void k_att(const float* __restrict__ x,
    const u16* __restrict__ WTattn, const float* __restrict__ b_attn,
    u16* __restrict__ att, u16* __restrict__ xbf) {
  __shared__ alignas(16) u16 XT[32768];  // [c-half 128][q 256], 64 KiB
  WAVE_SETUP;
  const int ch = blockIdx.x & 1;
  const int t = blockIdx.x >> 1;
  const int d = t & 31, w1 = (t >> 5) & 1, h1 = (t >> 6) & 1, b = t >> 7;
  const int B0 = (((b * 32 + h1 * 16) * 32 + w1 * 16) * 32 + d) * 256;

  // A: transposed stage, conflict-free: each thread = one c-row, 8 consecutive q,
  // single aligned u16x8 LDS write.
  for (int i = tid; i < 4096; i += 512) {
    int cloc = i & 127;
    int q8 = i >> 7;
    u16x8 pk;
#pragma unroll
    for (int jj = 0; jj < 8; ++jj) {
      int q = q8 * 8 + jj;
      pk[jj] = f2b(x[B0 + (q >> 4) * 262144 + (q & 15) * 8192 + ch * 128 + cloc]);
    }
    *(u16x8*)((char*)XT + lds_off(cloc, q8 * 16)) = pk;
  }
  // B: xbf emission — coalesced float4 re-read (L2-hot from loop A)
  for (int i = tid; i < 8192; i += 512) {
    int q = i >> 5;
    int c4 = (i & 31) << 2;
    const int gofs = B0 + (q >> 4) * 262144 + (q & 15) * 8192 + ch * 128 + c4;
    const f32x4 v = *(const f32x4*)(x + gofs);
    u16x4 pk;
    pk[0] = f2b(v[0]); pk[1] = f2b(v[1]); pk[2] = f2b(v[2]); pk[3] = f2b(v[3]);
    *(u16x4*)(xbf + gofs) = pk;
  }
  __syncthreads();

  f32x4 acc[8][2];
  zero_acc<8, 2>(acc);
  gemmT<8, 2>(
      [&](int i, int kk) { return ld_glb(WTattn, wm * 128 + i * 16 + lr, kk * 64 + lk * 16); },
      [&](int j, int kk) { return ld_lds(XT, wn * 32 + j * 16 + lr, kk * 64 + lk * 16); },
      acc);

  __syncthreads();  // XT dead; reuse as [p 256][c-half 128] bounce tile (256B pitch)
#pragma unroll
  for (int i = 0; i < 8; ++i)
#pragma unroll
    for (int j = 0; j < 2; ++j)
#pragma unroll
      for (int r = 0; r < 4; ++r) {
        int p = wm * 128 + i * 16 + lk * 4 + r;
        int cl = wn * 32 + j * 16 + lr;
        XT[lds_off256(p, cl * 2) >> 1] = f2b(acc[i][j][r] + b_attn[p]);
      }
  __syncthreads();
  u16* out = att + t * 65536;
  for (int i = tid; i < 4096; i += 512) {
    int p = i >> 4, sB = (i & 15) << 4;
    bf16x8 v = *(const bf16x8*)((const char*)XT + p * 256 + sB);
    int c8l = (sB ^ ((p & 15) << 4)) >> 1;
    *(bf16x8*)(out + p * 256 + ch * 128 + c8l) = v;
  }
}

// ---------- k_hw: h and w GEMMs from xbf; c-HALF blocks (80K LDS, 2/CU) ----------
__global__ __launch_bounds__(512, 2) void k_hw(const u16* __restrict__ xbf,
    const u16* __restrict__ WTh, const u16* __restrict__ WTw,
    u16* __restrict__ h_out, u16* __restrict__ w_out) {
  __shared__ alignas(16) u16 XS[32768];  // 64 KiB [pos 256][c-half 128], lds_offH
  __shared__ alignas(16) u16 BB[8192];   // 16 KiB bounce [64][128], lds_off256
  WAVE_SETUP;
  const int ch = blockIdx.x & 1;
  const int t = blockIdx.x >> 1;
  const int d = t & 31, w1 = (t >> 5) & 1, h1 = (t >> 6) & 1, b = t >> 7;
  const int B0 = (((b * 32 + h1 * 16) * 32 + w1 * 16) * 32 + d) * 256;
  u16* h_t = h_out + t * 65536 + ch * 128;
  u16* w_t = w_out + t * 65536 + ch * 128;

  for (int i = tid; i < 4096; i += 512) {
    int pos = i >> 4, c8 = (i & 15) << 3;
    u16x8 v = *(const u16x8*)(xbf + B0 + (pos >> 4) * 262144 + (pos & 15) * 8192 +
                              ch * 128 + c8);
    *(u16x8*)((char*)XS + lds_offH(pos, c8 * 2)) = v;
  }
  __syncthreads();

  // ---- h phases: 4 n-chunks ----
  for (int s = 0; s < 4; ++s) {
    f32x4 hacc[4][1];
    zero_acc<4, 1>(hacc);
    gemmT<4, 1>(
        [&](int i, int kk) {
          int k = kk * 32 + lk * 8;
          return *(const bf16x8*)((const char*)XS +
                                  lds_offH((k >> 4) * 16 + lr, (wm * 4 + i) * 32 + (k & 15) * 2));
        },
        [&](int j, int kk) { return ld_glb(WTh, s * 64 + wn * 16 + lr, kk * 64 + lk * 16); },
        hacc);
    __syncthreads();
#pragma unroll
    for (int i = 0; i < 4; ++i)
#pragma unroll
      for (int r = 0; r < 4; ++r)
        BB[lds_off256(wn * 16 + lk * 4 + r, ((wm * 4 + i) * 16 + lr) * 2) >> 1] =
            f2b(hacc[i][0][r]);
    __syncthreads();
    for (int i2 = tid; i2 < 1024; i2 += 512) {
      int posl = i2 >> 4, sB = (i2 & 15) << 4;
      bf16x8 v = *(const bf16x8*)((const char*)BB + posl * 256 + sB);
      int c8l = (sB ^ ((posl & 15) << 4)) >> 1;
      *(bf16x8*)(h_t + (s * 64 + posl) * 256 + c8l) = v;
    }
  }

  // ---- w phases: 4 n-chunks ----
  for (int q = 0; q < 4; ++q) {
    f32x4 wacc[4][1];
    zero_acc<4, 1>(wacc);
    gemmT<4, 1>(
        [&](int i, int kk) {
          int k = kk * 32 + lk * 8;
          return *(const bf16x8*)((const char*)XS +
                                  lds_offH(lr * 16 + (k >> 4), (wm * 4 + i) * 32 + (k & 15) * 2));
        },
        [&](int j, int kk) { return ld_glb(WTw, q * 64 + wn * 16 + lr, kk * 64 + lk * 16); },
        wacc);
    __syncthreads();
#pragma unroll
    for (int i = 0; i < 4; ++i)
#pragma unroll
      for (int r = 0; r < 4; ++r)
        BB[lds_off256((lk * 4 + r) * 4 + wn, ((wm * 4 + i) * 16 + lr) * 2) >> 1] =
            f2b(wacc[i][0][r]);
    __syncthreads();
    for (int i2 = tid; i2 < 1024; i2 += 512) {
      int rb = i2 >> 4, sB = (i2 & 15) << 4;
      bf16x8 v = *(const bf16x8*)((const char*)BB + rb * 256 + sB);
      int c8l = (sB ^ ((rb & 15) << 4)) >> 1;
      int pos = (rb >> 2) * 16 + 4 * q + (rb & 3);
      *(bf16x8*)(w_t + pos * 256 + c8l) = v;
    }
  }
}

// ---------- k_comb: single 64K tile; c-GEMM + streams + W1 + residual(xbf) -> x1 ----------
__global__ __launch_bounds__(512, 2) void k_comb(const u16* __restrict__ xbf,
    const u16* __restrict__ h_out, const u16* __restrict__ w_out, const u16* __restrict__ att,
    const float* __restrict__ bh, const float* __restrict__ bw, const float* __restrict__ bc,
    const u16* __restrict__ WTc, const u16* __restrict__ WT1, const float* __restrict__ b1,
    u16* __restrict__ x1) {
  __shared__ alignas(16) u16 T[32768];  // 64 KiB multi-use tile [posl 128][c 256]
  WAVE_SETUP;
  const int ph = blockIdx.x & 1;
  const int t = blockIdx.x >> 1;
  const int d = t & 31, w1 = (t >> 5) & 1, h1 = (t >> 6) & 1, b = t >> 7;
  const int B0 = (((b * 32 + h1 * 16) * 32 + w1 * 16) * 32 + d) * 256;
  const u16* h_t = h_out + t * 65536;
  const u16* w_t = w_out + t * 65536;
  const u16* att_t = att + t * 65536;

  // 1. stage from xbf (wide, coalesced)
  for (int i = tid; i < 4096; i += 512) {
    int posl = i >> 5, c8 = (i & 31) << 3;
    int pos = ph * 128 + posl;
    u16x8 v = *(const u16x8*)(xbf + B0 + (pos >> 4) * 262144 + (pos & 15) * 8192 + c8);
    *(u16x8*)((char*)T + lds_off(posl, c8 * 2)) = v;
  }
  __syncthreads();

  // 2. c-GEMM (Wc read once per block)
  f32x4 acc[4][4];
  zero_acc<4, 4>(acc);
  gemmT<4, 4>(
      [&](int i, int kk) { return ld_lds(T, wm * 64 + i * 16 + lr, kk * 64 + lk * 16); },
      [&](int j, int kk) { return ld_glb(WTc, wn * 64 + j * 16 + lr, kk * 64 + lk * 16); },
      acc);
  __syncthreads();  // all T reads retired

  // 3. T <- acc + bc + bh + bw
#pragma unroll
  for (int i = 0; i < 4; ++i) {
    int lh = ph * 8 + wm * 4 + i;
#pragma unroll
    for (int j = 0; j < 4; ++j) {
      float bcv = bc[wn * 64 + j * 16 + lr];
#pragma unroll
      for (int r = 0; r < 4; ++r) {
        int posl = wm * 64 + i * 16 + lk * 4 + r;
        int n = wn * 64 + j * 16 + lr;
        float v = acc[i][j][r] + bcv + bh[lh * 16 + lr] + bw[(lk * 4 + r) * 16 + lr];
        T[lds_off(posl, n * 2) >> 1] = f2b(v);
      }
    }
  }
  __syncthreads();

  // 4. streamed: T = (1+att) * (T + h + w)
  for (int i2 = tid; i2 < 4096; i2 += 512) {
    int posl = i2 >> 5, c8 = (i2 & 31) << 3;
    int pos = ph * 128 + posl;
    u16x8 hv = *(const u16x8*)(h_t + pos * 256 + c8);
    u16x8 wv = *(const u16x8*)(w_t + pos * 256 + c8);
    u16x8 av = *(const u16x8*)(att_t + pos * 256 + c8);
    u16x8* p = (u16x8*)((char*)T + lds_off(posl, c8 * 2));
    u16x8 cur = *p, o;
#pragma unroll
    for (int j = 0; j < 8; ++j)
      o[j] = f2b((1.0f + b2f(av[j])) * (b2f(cur[j]) + b2f(hv[j]) + b2f(wv[j])));
    *p = o;
  }
  __syncthreads();

  // 5. W1-GEMM (W1 read once per block)
  zero_acc<4, 4>(acc);
  gemmT<4, 4>(
      [&](int i, int kk) { return ld_lds(T, wm * 64 + i * 16 + lr, kk * 64 + lk * 16); },
      [&](int j, int kk) { return ld_glb(WT1, wn * 64 + j * 16 + lr, kk * 64 + lk * 16); },
      acc);
  __syncthreads();

  // 6. T <- acc + b1
#pragma unroll
  for (int i = 0; i < 4; ++i)
#pragma unroll
    for (int j = 0; j < 4; ++j) {
      float b1v = b1[wn * 64 + j * 16 + lr];
#pragma unroll
      for (int r = 0; r < 4; ++r) {
        int posl = wm * 64 + i * 16 + lk * 4 + r;
        int n = wn * 64 + j * 16 + lr;
        T[lds_off(posl, n * 2) >> 1] = f2b(acc[i][j][r] + b1v);
      }
    }
  __syncthreads();

  // 7. x1 = T + xbf (coalesced re-read, L3-hot); x-layout store
  for (int i2 = tid; i2 < 4096; i2 += 512) {
    int posl = i2 >> 5, sB = (i2 & 31) << 4;
    bf16x8 v = *(const bf16x8*)((const char*)T + posl * 512 + sB);
    int c8 = (sB ^ ((posl & 31) << 4)) >> 1;
    int pos = ph * 128 + posl;
    const int gofs = B0 + (pos >> 4) * 262144 + (pos & 15) * 8192 + c8;
    u16x8 xv = *(const u16x8*)(xbf + gofs);
    u16x8 o;
#pragma unroll
    for (int j = 0; j < 8; ++j) o[j] = f2b(b2f((u16)v[j]) + b2f(xv[j]));
    *(u16x8*)(x1 + gofs) = o;
  }
}

// ---------- k_tp: FUSED d+W2+W3, 128-row blocks, x1 kept in regs for residual ----------
__global__ __launch_bounds__(512, 2) void k_tp(const u16* __restrict__ x1,
    const u16* __restrict__ WTd, const u16* __restrict__ WT2, const u16* __restrict__ WT3p,
    const float* __restrict__ bd, const float* __restrict__ b2, const float* __restrict__ b3,
    float* __restrict__ outp) {
  __shared__ alignas(16) u16 T[32768];  // 64 KiB [R 128][c 256], R=(wloLoc,ld)
  WAVE_SETUP;
  const int bid = blockIdx.x;
  const int wg = bid & 3, d1 = (bid >> 2) & 1, h = (bid >> 3) & 31, b = bid >> 8;
  const int W0 = (b * 32 + h) * 32 + wg * 8;

  // 1. stage x1 rows; KEEP staged values in regs for the phase-6 residual
  u16x8 xkeep[8];
#pragma unroll
  for (int u = 0; u < 8; ++u) {
    int i = tid + u * 512;
    int Rl = i >> 5, c8 = (i & 31) << 3;
    const u16x8 v = *(const u16x8*)(x1 + (size_t)(W0 + (Rl >> 4)) * 8192 +
                                    (d1 * 16 + (Rl & 15)) * 256 + c8);
    xkeep[u] = v;
    *(u16x8*)((char*)T + lds_off(Rl, c8 * 2)) = v;
  }
  __syncthreads();

  // 2. d-GEMM: m=(wloLoc,lc) 128, n=(ld',g) 256, k=(ld,g') 256
  f32x4 acc[4][4];
  zero_acc<4, 4>(acc);
  gemmT<4, 4>(
      [&](int i, int kk) {
        int k = kk * 32 + lk * 8;
        int mt = wm * 4 + i;
        return *(const bf16x8*)((const char*)T + lds_off(mt * 16 + (k >> 4),
                                                         lr * 32 + (k & 15) * 2));
      },
      [&](int j, int kk) { return ld_glb(WTd, wn * 64 + j * 16 + lr, kk * 64 + lk * 16); },
      acc);
  __syncthreads();  // all T reads retired before overwrite

  // 3. T <- xd rows: (mloc,n) -> row=((mloc>>4)<<4)+(n>>4), col=((mloc&15)<<4)+(n&15)
#pragma unroll
  for (int i = 0; i < 4; ++i)
#pragma unroll
    for (int j = 0; j < 4; ++j)
#pragma unroll
      for (int r = 0; r < 4; ++r) {
        int mloc = wm * 64 + i * 16 + lk * 4 + r;
        int n = wn * 64 + j * 16 + lr;
        int row = ((mloc >> 4) << 4) + (n >> 4);
        int col = ((mloc & 15) << 4) + (n & 15);
        T[lds_off(row, col * 2) >> 1] = f2b(acc[i][j][r] + bd[n]);
      }
  __syncthreads();

  // 4. W2-GEMM: A = T (xd rows)
  zero_acc<4, 4>(acc);
  gemmT<4, 4>(
      [&](int i, int kk) { return ld_lds(T, (wm * 4 + i) * 16 + lr, kk * 64 + lk * 16); },
      [&](int j, int kk) { return ld_glb(WT2, wn * 64 + j * 16 + lr, kk * 64 + lk * 16); },
      acc);
  __syncthreads();  // T reads retired

  // 5. T <- acc + b2
#pragma unroll
  for (int i = 0; i < 4; ++i)
#pragma unroll
    for (int j = 0; j < 4; ++j) {
      float b2v = b2[wn * 64 + j * 16 + lr];
#pragma unroll
      for (int r = 0; r < 4; ++r) {
        int mloc = wm * 64 + i * 16 + lk * 4 + r;
        int n = wn * 64 + j * 16 + lr;
        T[lds_off(mloc, n * 2) >> 1] = f2b(acc[i][j][r] + b2v);
      }
    }
  __syncthreads();

  // 6. T += x1 (from regs — no global re-read)
#pragma unroll
  for (int u = 0; u < 8; ++u) {
    int i = tid + u * 512;
    int Rl = i >> 5, c8 = (i & 31) << 3;
    u16x8* p = (u16x8*)((char*)T + lds_off(Rl, c8 * 2));
    u16x8 cur = *p, o;
#pragma unroll
    for (int j = 0; j < 8; ++j) o[j] = f2b(b2f(cur[j]) + b2f(xkeep[u][j]));
    *p = o;
  }
  __syncthreads();

  // 7. W3-GEMM: A = T (x2 rows), B = (W3+I)^T
  zero_acc<4, 4>(acc);
  gemmT<4, 4>(
      [&](int i, int kk) { return ld_lds(T, (wm * 4 + i) * 16 + lr, kk * 64 + lk * 16); },
      [&](int j, int kk) { return ld_glb(WT3p, wn * 64 + j * 16 + lr, kk * 64 + lk * 16); },
      acc);

  // 8. fp32 out via 2-half T bounce ([64][256] f32 = 64K), float4 nt stores
  float* Tf = (float*)T;
#pragma unroll
  for (int half = 0; half < 2; ++half) {
    __syncthreads();  // T reads (W3 or prev half's stores) retired
    if (wm == half) {
#pragma unroll
      for (int i = 0; i < 4; ++i)
#pragma unroll
        for (int j = 0; j < 4; ++j)
#pragma unroll
          for (int r = 0; r < 4; ++r) {
            int row = i * 16 + lk * 4 + r;  // 0..63
            int n = wn * 64 + j * 16 + lr;
            Tf[row * 256 + n] = acc[i][j][r] + b3[n];
          }
    }
    __syncthreads();
    for (int i2 = tid; i2 < 4096; i2 += 512) {
      int row = i2 >> 6, c4 = (i2 & 63) << 2;
      int Rg = half * 64 + row;
      f32x4 v = *(const f32x4*)(Tf + row * 256 + c4);
      stf4_nt(outp + (size_t)(W0 + (Rg >> 4)) * 8192 + (d1 * 16 + (Rg & 15)) * 256 + c4, v);
    }
  }
}

extern "C" void kernel_launch(void* const* d_in, const int* in_sizes, int n_in,
                              void* d_out, int out_size, void* d_ws, size_t ws_size,
                              hipStream_t stream) {
  (void)in_sizes; (void)n_in; (void)out_size; (void)ws_size;
  const float* x      = (const float*)d_in[0];
  const float* W_h    = (const float*)d_in[1];
  const float* b_h    = (const float*)d_in[2];
  const float* W_w    = (const float*)d_in[3];
  const float* b_w    = (const float*)d_in[4];
  const float* W_c    = (const float*)d_in[5];
  const float* b_c    = (const float*)d_in[6];
  const float* W_d    = (const float*)d_in[7];
  const float* b_d    = (const float*)d_in[8];
  const float* W_attn = (const float*)d_in[9];
  const float* b_attn = (const float*)d_in[10];
  const float* W_1    = (const float*)d_in[11];
  const float* b_1    = (const float*)d_in[12];
  const float* W_2    = (const float*)d_in[13];
  const float* b_2    = (const float*)d_in[14];
  const float* W_3    = (const float*)d_in[15];
  const float* b_3    = (const float*)d_in[16];
  float* outp = (float*)d_out;

  u16* WT = (u16*)d_ws;             // 8 * 65536 bf16 (1 MiB)
  u16* R1 = WT + 8 * 65536;         // 64 MiB: xbf (x-layout) -> x1 (x-layout, block-local overlay)
  u16* R2 = R1 + 33554432;          // 64 MiB: att scratch
  u16* HOS = (u16*)d_out;           // h stream: first 64 MiB of d_out (dead after k_comb)
  u16* WOS = HOS + 33554432;        // w stream: second 64 MiB of d_out (dead after k_comb)

  // slots: 0:h 1:w 2:c 3:attn 4:W1 5:Wd 6:W2 7:W3(+I)
  k_pack_all<<<2048, 64, 0, stream>>>(W_h, W_w, W_c, W_attn, W_1, W_d, W_2, W_3, WT);

  k_att <<<1024, 512, 0, stream>>>(x, WT + 3 * 65536, b_attn, R2, R1);
  k_hw  <<<1024, 512, 0, stream>>>(R1, WT + 0 * 65536, WT + 1 * 65536, HOS, WOS);
  k_comb<<<1024, 512, 0, stream>>>(R1, HOS, WOS, R2, b_h, b_w, b_c,
                                   WT + 2 * 65536, WT + 4 * 65536, b_1, R1);
  k_tp  <<<1024, 512, 0, stream>>>(R1, WT + 5 * 65536, WT + 6 * 65536, WT + 7 * 65536,
                                   b_d, b_2, b_3, outp);
}